// Round 4
// baseline (1546.029 us; speedup 1.0000x reference)
//
#include <hip/hip_runtime.h>
#include <math.h>

#define FEAT_DIM 256
#define NCLS 21
#define TEMP 0.1f
#define GPX 256                 // pixels per stolen work quantum (one wave)
#define NCOPY 4                 // replicated LDS accumulators
#define CSTRIDE (NCLS * 257)    // 5397 dwords per copy: bank(c,d) = (21r+c+d)%32

// ---------------------------------------------------------------------------
// Kernel 1: per-pixel inverse L2 norm. R0-proven shape: thread owns 4 pixels
// (float4 column), streams 256 channel rows, no LDS, no barriers.
// Wave-level work stealing balances the 2304 quanta across 2048 waves.
// ---------------------------------------------------------------------------
__global__ __launch_bounds__(256)
void k_norms(const float* __restrict__ feat, float* __restrict__ inv_norm,
             int* __restrict__ cnt, int N, int ngroups) {
    const int lane = threadIdx.x & 63;
    for (;;) {
        int g = 0;
        if (lane == 0) g = atomicAdd(cnt, 1);
        g = __shfl(g, 0);
        if (g >= ngroups) break;

        const int n0 = g * GPX + lane * 4;
        float ssx = 0.f, ssy = 0.f, ssz = 0.f, ssw = 0.f;
        #pragma unroll 8
        for (int d = 0; d < FEAT_DIM; ++d) {
            float4 v = *reinterpret_cast<const float4*>(feat + (size_t)d * N + n0);
            ssx = fmaf(v.x, v.x, ssx);
            ssy = fmaf(v.y, v.y, ssy);
            ssz = fmaf(v.z, v.z, ssz);
            ssw = fmaf(v.w, v.w, ssw);
        }
        float4 r;
        r.x = 1.0f / fmaxf(sqrtf(ssx), 1e-12f);
        r.y = 1.0f / fmaxf(sqrtf(ssy), 1e-12f);
        r.z = 1.0f / fmaxf(sqrtf(ssz), 1e-12f);
        r.w = 1.0f / fmaxf(sqrtf(ssw), 1e-12f);
        *reinterpret_cast<float4*>(inv_norm + n0) = r;
    }
}

// ---------------------------------------------------------------------------
// Kernel 2: scatter-add normalized features into per-class sums.
// Same streaming shape as k_norms; accumulation via ds_add_f32 into 4
// REPLICATED LDS copies (copy = lane&3) so same-class lanes rarely collide
// on one address. Per channel: 1 float4 load + 4 mul + 4 ds_add.
// ---------------------------------------------------------------------------
__global__ __launch_bounds__(1024)
void k_scatter(const float* __restrict__ feat, const float* __restrict__ inv,
               const int* __restrict__ lab,
               float* __restrict__ gsum, float* __restrict__ gcnt,
               int* __restrict__ cnt, int N, int ngroups) {
    __shared__ float s_sum[NCOPY * CSTRIDE];   // 86.4 KB
    __shared__ float s_cnt[NCOPY * 32];

    const int tid = threadIdx.x, lane = tid & 63;

    for (int i = tid; i < NCOPY * CSTRIDE; i += blockDim.x) s_sum[i] = 0.f;
    if (tid < NCOPY * 32) s_cnt[tid] = 0.f;
    __syncthreads();

    const int cp = (lane & 3) * CSTRIDE;

    for (;;) {
        int g = 0;
        if (lane == 0) g = atomicAdd(cnt, 1);
        g = __shfl(g, 0);
        if (g >= ngroups) break;

        const int n0 = g * GPX + lane * 4;
        const int4   L  = *reinterpret_cast<const int4*>(lab + n0);
        const float4 iv = *reinterpret_cast<const float4*>(inv + n0);

        atomicAdd(&s_cnt[(lane & 3) * 32 + L.x], 1.f);
        atomicAdd(&s_cnt[(lane & 3) * 32 + L.y], 1.f);
        atomicAdd(&s_cnt[(lane & 3) * 32 + L.z], 1.f);
        atomicAdd(&s_cnt[(lane & 3) * 32 + L.w], 1.f);

        float* a0 = &s_sum[cp + L.x * 257];
        float* a1 = &s_sum[cp + L.y * 257];
        float* a2 = &s_sum[cp + L.z * 257];
        float* a3 = &s_sum[cp + L.w * 257];

        #pragma unroll 8
        for (int d = 0; d < FEAT_DIM; ++d) {
            float4 v = *reinterpret_cast<const float4*>(feat + (size_t)d * N + n0);
            atomicAdd(a0 + d, v.x * iv.x);
            atomicAdd(a1 + d, v.y * iv.y);
            atomicAdd(a2 + d, v.z * iv.z);
            atomicAdd(a3 + d, v.w * iv.w);
        }
    }
    __syncthreads();

    // merge 4 copies -> one global atomic per element per block
    for (int i = tid; i < NCLS * FEAT_DIM; i += blockDim.x) {
        const int c = i / FEAT_DIM, d = i - c * FEAT_DIM;
        float v = 0.f;
        #pragma unroll
        for (int r = 0; r < NCOPY; ++r) v += s_sum[r * CSTRIDE + c * 257 + d];
        if (v != 0.f) atomicAdd(&gsum[i], v);
    }
    if (tid < NCLS) {
        float v = 0.f;
        #pragma unroll
        for (int r = 0; r < NCOPY; ++r) v += s_cnt[r * 32 + tid];
        atomicAdd(&gcnt[tid], v);
    }
}

// ---------------------------------------------------------------------------
// Kernel 3: finalize. means -> 21x21 logits -> masked contrastive loss.
// ---------------------------------------------------------------------------
__global__ void k_final(const float* __restrict__ gsum,
                        const float* __restrict__ gcnt,
                        const float* __restrict__ proto,
                        float* __restrict__ out) {
    __shared__ float s_mean[NCLS * 257];
    __shared__ float s_icnt[NCLS];
    __shared__ float s_log[NCLS * NCLS];
    __shared__ float s_term[NCLS];

    if (threadIdx.x < NCLS)
        s_icnt[threadIdx.x] = 1.0f / fmaxf(gcnt[threadIdx.x], 1.0f);
    __syncthreads();

    for (int i = threadIdx.x; i < NCLS * FEAT_DIM; i += blockDim.x) {
        const int c = i / FEAT_DIM, d = i - c * FEAT_DIM;
        s_mean[c * 257 + d] = gsum[i] * s_icnt[c];
    }
    __syncthreads();

    for (int p = threadIdx.x; p < NCLS * NCLS; p += blockDim.x) {
        const int c = p / NCLS, j = p - c * NCLS;
        float acc = 0.f;
        #pragma unroll 8
        for (int d = 0; d < FEAT_DIM; ++d)
            acc += s_mean[c * 257 + d] * proto[j * FEAT_DIM + d];
        s_log[p] = acc / TEMP;
    }
    __syncthreads();

    if (threadIdx.x >= 1 && threadIdx.x < NCLS) {
        const int c = threadIdx.x;
        float m = -INFINITY;
        for (int j = 0; j < NCLS; ++j) m = fmaxf(m, s_log[c * NCLS + j]);
        float den = 0.f;
        for (int j = 1; j < NCLS; ++j) den += expf(s_log[c * NCLS + j] - m);
        s_term[c] = logf(den) - (s_log[c * NCLS + c] - m);
    }
    __syncthreads();

    if (threadIdx.x == 0) {
        float acc = 0.f;
        for (int c = 1; c < NCLS; ++c) acc += s_term[c];
        out[0] = acc / (float)(NCLS - 1);
    }
}

// ---------------------------------------------------------------------------
extern "C" void kernel_launch(void* const* d_in, const int* in_sizes, int n_in,
                              void* d_out, int out_size, void* d_ws, size_t ws_size,
                              hipStream_t stream) {
    const float* feat  = (const float*)d_in[0];
    const float* proto = (const float*)d_in[1];
    const int*   lab   = (const int*)d_in[3];   // d_in[2] "outputs" unused

    const int N = in_sizes[3];                  // 589824 = 2304 * 256
    const int ngroups = N / GPX;                // 2304

    // workspace: [0..15] int counters | iv[N] | gsum[21*256] | gcnt[21]
    int*   cnt  = (int*)d_ws;
    float* iv   = (float*)d_ws + 16;
    float* gsum = iv + N;
    float* gcnt = gsum + NCLS * FEAT_DIM;

    hipMemsetAsync(d_ws, 0, 64, stream);
    hipMemsetAsync(gsum, 0, (NCLS * FEAT_DIM + NCLS) * sizeof(float), stream);

    k_norms  <<<512, 256, 0, stream>>>(feat, iv, cnt + 0, N, ngroups);
    k_scatter<<<256, 1024, 0, stream>>>(feat, iv, lab, gsum, gcnt, cnt + 1, N, ngroups);
    k_final  <<<1, 256, 0, stream>>>(gsum, gcnt, proto, (float*)d_out);
}

// Round 5
// 304.047 us; speedup vs baseline: 5.0848x; 5.0848x over previous
//
#include <hip/hip_runtime.h>
#include <math.h>

#define FEAT_DIM 256
#define NCLS 21
#define TEMP 0.1f
#define BPX 256                 // pixels per batch
#define SPX 64                  // pixels per sub-batch (one wave-width)
#define NW 8                    // waves per block
#define CPW 32                  // channels per wave
#define TSTRIDE 68              // tile row stride in dwords (64 px + pad, b128-friendly)

typedef float f32x4 __attribute__((ext_vector_type(4)));
typedef int   i32x4 __attribute__((ext_vector_type(4)));

// ---------------------------------------------------------------------------
// Kernel 1: per-pixel inverse L2 norm — EXACT R0 shape (measured ~130us).
// Thread owns 4 consecutive pixels (float4), streams 256 channel rows.
// No LDS, no barriers, no atomics, static assignment.
// ---------------------------------------------------------------------------
__global__ void k_norms(const float* __restrict__ feat,
                        float* __restrict__ inv_norm, int N) {
    int t  = blockIdx.x * blockDim.x + threadIdx.x;
    int n0 = t * 4;
    if (n0 >= N) return;

    float ssx = 0.f, ssy = 0.f, ssz = 0.f, ssw = 0.f;
    #pragma unroll 8
    for (int d = 0; d < FEAT_DIM; ++d) {
        float4 v = *reinterpret_cast<const float4*>(feat + (size_t)d * N + n0);
        ssx += v.x * v.x;
        ssy += v.y * v.y;
        ssz += v.z * v.z;
        ssw += v.w * v.w;
    }
    float4 r;
    r.x = 1.0f / fmaxf(sqrtf(ssx), 1e-12f);
    r.y = 1.0f / fmaxf(sqrtf(ssy), 1e-12f);
    r.z = 1.0f / fmaxf(sqrtf(ssz), 1e-12f);
    r.w = 1.0f / fmaxf(sqrtf(ssw), 1e-12f);
    *reinterpret_cast<float4*>(inv_norm + n0) = r;
}

// ---------------------------------------------------------------------------
// Kernel 2: scatter-add normalized features into per-class sums with ZERO
// atomics in the hot path (LDS f32 atomics cost ~266cy/instr: per-lane
// serialized — measured R0/R4). Ownership makes every accumulator cell
// (h, c, d) private to one thread:
//   wave w owns channels [w*32, w*32+32); lane&31 = channel; lane>>5 = h
//   (pixel half). Flush = plain ds_read+add+ds_write.
// Per batch (256 px): per-wave-private transpose tile (no barriers in loop),
// ballot-sort labels in registers, stage by rank, b128 row reads, register
// accumulate with flush on (wave-uniform-per-half) class change.
// ---------------------------------------------------------------------------
__global__ __launch_bounds__(512, 1)
void k_scatter(const float* __restrict__ feat, const float* __restrict__ iv,
               const int* __restrict__ lab,
               float* __restrict__ gsum, float* __restrict__ gcnt, int N) {
    __shared__ float s_tile[NW][CPW * TSTRIDE];      // 69632 B (private per wave)
    __shared__ float s_acc[2 * NCLS * FEAT_DIM];     // 43008 B (cells lane-private)
    __shared__ float s_ivr[NW][SPX];                 // 2048 B  (iv by rank)
    __shared__ int   s_scl[NW][SPX];                 // 2048 B  (class by rank)

    const int tid = threadIdx.x, lane = tid & 63, w = tid >> 6;
    const int nb = N / BPX;                          // 2304 (N divisible)

    for (int i = tid; i < 2 * NCLS * FEAT_DIM; i += 512) s_acc[i] = 0.f;
    __syncthreads();

    const int c4 = lane >> 4, p16 = lane & 15;       // staging role
    const int h = lane >> 5, chan = lane & 31;       // accumulate role
    const int dbase = w * CPW;
    float* tile = s_tile[w];
    float cntacc = 0.f;                              // wave0 lane c: count of class c

    for (int g = blockIdx.x; g < nb; g += gridDim.x) {
        const size_t n0 = (size_t)g * BPX;
        #pragma unroll 1
        for (int sub = 0; sub < 4; ++sub) {
            const size_t ns = n0 + sub * SPX;

            // ---- labels + iv (lane = pixel), ballot-sort in registers
            const int   myl  = lab[ns + lane];
            const float myiv = iv[ns + lane];
            int myrank = 0, base = 0;
            #pragma unroll 1
            for (int c = 0; c < NCLS; ++c) {
                const unsigned long long m = __ballot(myl == c);
                const int cnt = __popcll(m);
                if (myl == c)
                    myrank = base + __popcll(m & ((1ull << lane) - 1ull));
                if (w == 0 && lane == c) cntacc += (float)cnt;
                base += cnt;
            }
            s_ivr[w][myrank] = myiv;                 // wave-private, no race
            s_scl[w][myrank] = myl;

            // ---- stage 32ch x 64px, permuted by rank (4 scattered w32/float4)
            const int r0 = __shfl(myrank, p16 * 4 + 0);
            const int r1 = __shfl(myrank, p16 * 4 + 1);
            const int r2 = __shfl(myrank, p16 * 4 + 2);
            const int r3 = __shfl(myrank, p16 * 4 + 3);
            #pragma unroll
            for (int j = 0; j < 8; ++j) {
                const int row = j * 4 + c4;          // local channel 0..31
                const float4 v = *reinterpret_cast<const float4*>(
                    feat + (size_t)(dbase + row) * N + ns + p16 * 4);
                float* tr = tile + row * TSTRIDE;
                tr[r0] = v.x; tr[r1] = v.y; tr[r2] = v.z; tr[r3] = v.w;
            }
            asm volatile("s_waitcnt lgkmcnt(0)" ::: "memory");  // own writes -> own reads

            // ---- accumulate: lane owns (h, chan); 32 sorted px, b128 reads
            const float* tr  = tile + chan * TSTRIDE + h * 32;
            const float* pir = s_ivr[w] + h * 32;
            const int*   psc = s_scl[w] + h * 32;

            f32x4 tv[8], vv[8];
            i32x4 sc[8];
            #pragma unroll
            for (int j = 0; j < 8; ++j) {
                tv[j] = *reinterpret_cast<const f32x4*>(tr + 4 * j);
                vv[j] = *reinterpret_cast<const f32x4*>(pir + 4 * j);
                sc[j] = *reinterpret_cast<const i32x4*>(psc + 4 * j);
            }

            float acc = 0.f;
            int ccur = sc[0][0];
            #pragma unroll
            for (int k = 0; k < 32; ++k) {
                const int ck = sc[k >> 2][k & 3];    // static index (rule 20)
                if (ck != ccur) {                     // uniform per half
                    float* cell = &s_acc[(h * NCLS + ccur) * FEAT_DIM + dbase + chan];
                    *cell += acc;                     // plain RMW, cell private
                    acc = 0.f; ccur = ck;
                }
                acc = fmaf(tv[k >> 2][k & 3], vv[k >> 2][k & 3], acc);
            }
            float* cell = &s_acc[(h * NCLS + ccur) * FEAT_DIM + dbase + chan];
            *cell += acc;
        }
    }

    __syncthreads();
    // merge halves -> one global atomic per cell per block (5376/block, spread)
    for (int i = tid; i < NCLS * FEAT_DIM; i += 512) {
        const float v = s_acc[i] + s_acc[NCLS * FEAT_DIM + i];
        if (v != 0.f) atomicAdd(&gsum[i], v);
    }
    if (w == 0 && lane < NCLS) atomicAdd(&gcnt[lane], cntacc);
}

// ---------------------------------------------------------------------------
// Kernel 3: finalize. means -> 21x21 logits -> masked contrastive loss.
// ---------------------------------------------------------------------------
__global__ void k_final(const float* __restrict__ gsum,
                        const float* __restrict__ gcnt,
                        const float* __restrict__ proto,
                        float* __restrict__ out) {
    __shared__ float s_mean[NCLS * 257];
    __shared__ float s_icnt[NCLS];
    __shared__ float s_log[NCLS * NCLS];
    __shared__ float s_term[NCLS];

    if (threadIdx.x < NCLS)
        s_icnt[threadIdx.x] = 1.0f / fmaxf(gcnt[threadIdx.x], 1.0f);
    __syncthreads();

    for (int i = threadIdx.x; i < NCLS * FEAT_DIM; i += blockDim.x) {
        const int c = i / FEAT_DIM, d = i - c * FEAT_DIM;
        s_mean[c * 257 + d] = gsum[i] * s_icnt[c];
    }
    __syncthreads();

    for (int p = threadIdx.x; p < NCLS * NCLS; p += blockDim.x) {
        const int c = p / NCLS, j = p - c * NCLS;
        float acc = 0.f;
        #pragma unroll 8
        for (int d = 0; d < FEAT_DIM; ++d)
            acc += s_mean[c * 257 + d] * proto[j * FEAT_DIM + d];
        s_log[p] = acc / TEMP;
    }
    __syncthreads();

    if (threadIdx.x >= 1 && threadIdx.x < NCLS) {
        const int c = threadIdx.x;
        float m = -INFINITY;
        for (int j = 0; j < NCLS; ++j) m = fmaxf(m, s_log[c * NCLS + j]);
        float den = 0.f;
        for (int j = 1; j < NCLS; ++j) den += expf(s_log[c * NCLS + j] - m);
        s_term[c] = logf(den) - (s_log[c * NCLS + c] - m);
    }
    __syncthreads();

    if (threadIdx.x == 0) {
        float acc = 0.f;
        for (int c = 1; c < NCLS; ++c) acc += s_term[c];
        out[0] = acc / (float)(NCLS - 1);
    }
}

// ---------------------------------------------------------------------------
extern "C" void kernel_launch(void* const* d_in, const int* in_sizes, int n_in,
                              void* d_out, int out_size, void* d_ws, size_t ws_size,
                              hipStream_t stream) {
    const float* feat  = (const float*)d_in[0];
    const float* proto = (const float*)d_in[1];
    const int*   lab   = (const int*)d_in[3];   // d_in[2] "outputs" unused

    const int N = in_sizes[3];                  // 589824 = 2304 * 256

    float* ivb  = (float*)d_ws;                 // [N]
    float* gsum = ivb + N;                      // [21*256]
    float* gcnt = gsum + NCLS * FEAT_DIM;       // [21]

    hipMemsetAsync(gsum, 0, (NCLS * FEAT_DIM + NCLS) * sizeof(float), stream);

    const int nthr   = (N + 3) / 4;
    const int blocks = (nthr + 255) / 256;      // 576
    k_norms  <<<blocks, 256, 0, stream>>>(feat, ivb, N);
    k_scatter<<<256, 512, 0, stream>>>(feat, ivb, lab, gsum, gcnt, N);
    k_final  <<<1, 256, 0, stream>>>(gsum, gcnt, proto, (float*)d_out);
}

// Round 6
// 197.944 us; speedup vs baseline: 7.8104x; 1.5360x over previous
//
#include <hip/hip_runtime.h>
#include <math.h>

#define FEAT_DIM 256
#define NCLS 21
#define TEMP 0.1f
#define BPX 256                 // pixels per batch
#define SPX 64                  // pixels per sub-batch (one wave-width)
#define NW 8                    // waves per block
#define CPW 32                  // channels per wave
#define TSTRIDE 68              // tile row stride (64 px + pad, 16B-aligned rows)

typedef float f32x4 __attribute__((ext_vector_type(4)));
typedef int   i32x4 __attribute__((ext_vector_type(4)));

// ---------------------------------------------------------------------------
// Single-pass fused kernel: reads features from HBM exactly ONCE.
// Per 64-px sub-batch:
//   1. ballot-sort labels in registers (all waves redundantly -> identical
//      ranks, no sync needed)
//   2. in-register squared-norm partials from the loaded float4s,
//      shfl_xor-reduce over channel groups, b128 write of wave partials
//   3. stage 32ch x 64px into wave-PRIVATE LDS tile, permuted by rank
//   4. issue NEXT sub-batch's global loads (latency hides under 6.)
//   5. one __syncthreads(); each lane combines 8 wave partials -> iv
//      (written to wave-private s_ivr copy -> no second barrier)
//   6. accumulate: lane owns (half, chan) -> every s_acc cell is private to
//      one thread; flush on class change = plain LDS RMW (~12cy, NOT the
//      ~266cy LDS atomic measured in R0/R4)
// s_ssp is double-buffered so the single barrier per sub is race-free.
// ---------------------------------------------------------------------------
__global__ __launch_bounds__(512, 1)
void k_fused(const float* __restrict__ feat, const int* __restrict__ lab,
             float* __restrict__ gsum, float* __restrict__ gcnt, int N) {
    __shared__ float        s_tile[NW][CPW * TSTRIDE];   // 69632 B, per-wave
    __shared__ float        s_acc[2 * NCLS * FEAT_DIM];  // 43008 B, cells private
    __shared__ float        s_ssp[2][NW][SPX];           // 4096 B, dbuf partials
    __shared__ float        s_ivr[NW][SPX];              // 2048 B, per-wave iv
    __shared__ unsigned int s_scb[NW][16];               // 512 B, class bytes

    const int tid = threadIdx.x, lane = tid & 63, w = tid >> 6;
    const int c4 = lane >> 4, p16 = lane & 15;           // staging role
    const int h = lane >> 5, chan = lane & 31;           // accumulate role
    const int dbase = w * CPW;
    float* tile = s_tile[w];

    for (int i = tid; i < 2 * NCLS * FEAT_DIM; i += 512) s_acc[i] = 0.f;
    __syncthreads();

    const int nb  = N / BPX;                 // 2304
    const int per = nb / gridDim.x;          // 9
    const int NIT = per * 4;                 // 36 sub-batches per block
    const size_t base0 = (size_t)blockIdx.x * per * BPX;

    float cntacc = 0.f;                      // w0 lane c: running count class c

    float4 VA[8], VB[8];
    int labA = 0, labB = 0;

    // prologue: load sub-batch 0
    {
        labA = lab[base0 + lane];
        #pragma unroll
        for (int j = 0; j < 8; ++j)
            VA[j] = *reinterpret_cast<const float4*>(
                feat + (size_t)(dbase + j * 4 + c4) * N + base0 + 4 * p16);
    }

    auto body = [&](int it, float4 (&VC)[8], int labc,
                    float4 (&VN)[8], int& labn) {
        // ---- 1. ballot-sort (registers only, identical across waves)
        int myrank = 0, bacc = 0;
        #pragma unroll 1
        for (int c = 0; c < NCLS; ++c) {
            const unsigned long long m = __ballot(labc == c);
            const int cnt = __popcll(m);
            if (labc == c)
                myrank = bacc + __popcll(m & ((1ull << lane) - 1ull));
            if (w == 0 && lane == c) cntacc += (float)cnt;
            bacc += cnt;
        }
        ((unsigned char*)s_scb[w])[myrank] = (unsigned char)labc;

        // ---- 2. in-register squared-norm partials + xor-reduce over c4
        f32x4 ssv = {0.f, 0.f, 0.f, 0.f};
        #pragma unroll
        for (int j = 0; j < 8; ++j) {
            ssv[0] = fmaf(VC[j].x, VC[j].x, ssv[0]);
            ssv[1] = fmaf(VC[j].y, VC[j].y, ssv[1]);
            ssv[2] = fmaf(VC[j].z, VC[j].z, ssv[2]);
            ssv[3] = fmaf(VC[j].w, VC[j].w, ssv[3]);
        }
        #pragma unroll
        for (int i = 0; i < 4; ++i) {
            ssv[i] += __shfl_xor(ssv[i], 16);
            ssv[i] += __shfl_xor(ssv[i], 32);
        }
        if (c4 == 0)
            *(f32x4*)&s_ssp[it & 1][w][4 * p16] = ssv;

        // ---- 3. stage by rank into wave-private tile
        const int r0 = __shfl(myrank, 4 * p16 + 0);
        const int r1 = __shfl(myrank, 4 * p16 + 1);
        const int r2 = __shfl(myrank, 4 * p16 + 2);
        const int r3 = __shfl(myrank, 4 * p16 + 3);
        #pragma unroll
        for (int j = 0; j < 8; ++j) {
            float* trw = tile + (j * 4 + c4) * TSTRIDE;
            trw[r0] = VC[j].x; trw[r1] = VC[j].y;
            trw[r2] = VC[j].z; trw[r3] = VC[j].w;
        }

        // ---- 4. issue next sub-batch's loads (hide HBM under accumulate)
        if (it + 1 < NIT) {
            const int it2 = it + 1;
            const size_t ns2 = base0 + (size_t)(it2 >> 2) * BPX + (it2 & 3) * SPX;
            labn = lab[ns2 + lane];
            #pragma unroll
            for (int j = 0; j < 8; ++j)
                VN[j] = *reinterpret_cast<const float4*>(
                    feat + (size_t)(dbase + j * 4 + c4) * N + ns2 + 4 * p16);
        }

        // ---- 5. cross-wave norm combine -> iv (wave-private copy)
        __syncthreads();
        float ss = 0.f;
        #pragma unroll
        for (int q = 0; q < NW; ++q) ss += s_ssp[it & 1][q][lane];
        s_ivr[w][lane] = 1.0f / fmaxf(sqrtf(ss), 1e-12f);

        // ---- 6. accumulate: lane owns (h, chan); flush = plain private RMW
        f32x4 tv[8], vv[8];
        i32x4 cwv[2];
        const float* trr = tile + chan * TSTRIDE + h * 32;
        const float* pir = s_ivr[w] + h * 32;
        const unsigned int* pcw = s_scb[w] + h * 8;
        #pragma unroll
        for (int j = 0; j < 8; ++j) tv[j] = *(const f32x4*)(trr + 4 * j);
        #pragma unroll
        for (int j = 0; j < 8; ++j) vv[j] = *(const f32x4*)(pir + 4 * j);
        cwv[0] = *(const i32x4*)(pcw);
        cwv[1] = *(const i32x4*)(pcw + 4);

        float acc = 0.f;
        int ccur = cwv[0][0] & 255;
        #pragma unroll
        for (int k = 0; k < 32; ++k) {
            const int word = cwv[k >> 4][(k >> 2) & 3];   // static idx (rule 20)
            const int ck = (word >> (8 * (k & 3))) & 255;
            if (ck != ccur) {
                s_acc[(h * NCLS + ccur) * FEAT_DIM + dbase + chan] += acc;
                acc = 0.f; ccur = ck;
            }
            acc = fmaf(tv[k >> 2][k & 3], vv[k >> 2][k & 3], acc);
        }
        s_acc[(h * NCLS + ccur) * FEAT_DIM + dbase + chan] += acc;
    };

    for (int it = 0; it < NIT; it += 2) {       // NIT=36, even
        body(it,     VA, labA, VB, labB);
        body(it + 1, VB, labB, VA, labA);
    }

    __syncthreads();
    // merge halves -> one global atomic per cell per block
    for (int i = tid; i < NCLS * FEAT_DIM; i += 512) {
        const float v = s_acc[i] + s_acc[NCLS * FEAT_DIM + i];
        if (v != 0.f) atomicAdd(&gsum[i], v);
    }
    if (w == 0 && lane < NCLS) atomicAdd(&gcnt[lane], cntacc);
}

// ---------------------------------------------------------------------------
// Finalize: means -> 21x21 logits -> masked contrastive loss.
// ---------------------------------------------------------------------------
__global__ void k_final(const float* __restrict__ gsum,
                        const float* __restrict__ gcnt,
                        const float* __restrict__ proto,
                        float* __restrict__ out) {
    __shared__ float s_mean[NCLS * 257];
    __shared__ float s_icnt[NCLS];
    __shared__ float s_log[NCLS * NCLS];
    __shared__ float s_term[NCLS];

    if (threadIdx.x < NCLS)
        s_icnt[threadIdx.x] = 1.0f / fmaxf(gcnt[threadIdx.x], 1.0f);
    __syncthreads();

    for (int i = threadIdx.x; i < NCLS * FEAT_DIM; i += blockDim.x) {
        const int c = i / FEAT_DIM, d = i - c * FEAT_DIM;
        s_mean[c * 257 + d] = gsum[i] * s_icnt[c];
    }
    __syncthreads();

    for (int p = threadIdx.x; p < NCLS * NCLS; p += blockDim.x) {
        const int c = p / NCLS, j = p - c * NCLS;
        float acc = 0.f;
        #pragma unroll 8
        for (int d = 0; d < FEAT_DIM; ++d)
            acc += s_mean[c * 257 + d] * proto[j * FEAT_DIM + d];
        s_log[p] = acc / TEMP;
    }
    __syncthreads();

    if (threadIdx.x >= 1 && threadIdx.x < NCLS) {
        const int c = threadIdx.x;
        float m = -INFINITY;
        for (int j = 0; j < NCLS; ++j) m = fmaxf(m, s_log[c * NCLS + j]);
        float den = 0.f;
        for (int j = 1; j < NCLS; ++j) den += expf(s_log[c * NCLS + j] - m);
        s_term[c] = logf(den) - (s_log[c * NCLS + c] - m);
    }
    __syncthreads();

    if (threadIdx.x == 0) {
        float acc = 0.f;
        for (int c = 1; c < NCLS; ++c) acc += s_term[c];
        out[0] = acc / (float)(NCLS - 1);
    }
}

// ---------------------------------------------------------------------------
extern "C" void kernel_launch(void* const* d_in, const int* in_sizes, int n_in,
                              void* d_out, int out_size, void* d_ws, size_t ws_size,
                              hipStream_t stream) {
    const float* feat  = (const float*)d_in[0];
    const float* proto = (const float*)d_in[1];
    const int*   lab   = (const int*)d_in[3];   // d_in[2] "outputs" unused

    const int N = in_sizes[3];                  // 589824 = 2304 * 256

    float* gsum = (float*)d_ws;                 // [21*256]
    float* gcnt = gsum + NCLS * FEAT_DIM;       // [21]

    hipMemsetAsync(gsum, 0, (NCLS * FEAT_DIM + NCLS) * sizeof(float), stream);

    k_fused<<<256, 512, 0, stream>>>(feat, lab, gsum, gcnt, N);
    k_final<<<1, 256, 0, stream>>>(gsum, gcnt, proto, (float*)d_out);
}